// Round 3
// baseline (424.416 us; speedup 1.0000x reference)
//
#include <hip/hip_runtime.h>
#include <math.h>

#define HDIM 1024
#define SDIM 2048
#define BDIM 32

// K1: v[b][h] = sum_k hidden[b][k] * W[k][h]
// grid = B * (H/256) = 128 blocks, 256 threads.
// W[k*H+h] coalesced across threads; hidden[b*H+k] is wave-uniform -> s_load.
__global__ void k1_hidW(const float* __restrict__ hidden,
                        const float* __restrict__ W,
                        float* __restrict__ v) {
    const int TILES = HDIM / 256;
    int tile = blockIdx.x % TILES;
    int b    = blockIdx.x / TILES;
    int h    = tile * 256 + threadIdx.x;
    const float* hb = hidden + b * HDIM;
    const float* Wh = W + h;
    float acc = 0.f;
#pragma unroll 8
    for (int k = 0; k < HDIM; ++k) {
        acc = fmaf(hb[k], Wh[(size_t)k * HDIM], acc);
    }
    v[b * HDIM + h] = acc;
}

// K2: e[b][s] = dot(enc[s,b,:], v[b,:])
// One wave per (s,b) pair. 4 waves/block -> grid = S*B/4 = 16384 blocks.
// Each lane: 4x float4 of enc (coalesced 1KiB/wave/instr) dotted with v (L2-hot).
__global__ void k2_energy(const float* __restrict__ enc,
                          const float* __restrict__ v,
                          float* __restrict__ e) {
    int wave = threadIdx.x >> 6;
    int lane = threadIdx.x & 63;
    int p = blockIdx.x * 4 + wave;          // 0 .. S*B-1
    int b = p & (BDIM - 1);
    int s = p >> 5;                          // p / BDIM
    const float4* encp = (const float4*)(enc + (size_t)(s * BDIM + b) * HDIM);
    const float4* vp   = (const float4*)(v + b * HDIM);
    float acc = 0.f;
#pragma unroll
    for (int j = 0; j < 4; ++j) {
        float4 a = encp[lane + j * 64];
        float4 w = vp[lane + j * 64];
        acc += a.x * w.x + a.y * w.y + a.z * w.z + a.w * w.w;
    }
#pragma unroll
    for (int off = 32; off; off >>= 1) acc += __shfl_xor(acc, off, 64);
    if (lane == 0) e[b * SDIM + s] = acc;
}

// K3: out[b][s] = softmax over s of e[b][:]. One block per b, 256 threads x 8 vals.
__global__ void k3_softmax(const float* __restrict__ e,
                           float* __restrict__ out) {
    __shared__ float red[8];
    int b = blockIdx.x;
    int tid = threadIdx.x;
    int wave = tid >> 6, lane = tid & 63;
    float vals[8];
    float m = -INFINITY;
#pragma unroll
    for (int j = 0; j < 8; ++j) {
        vals[j] = e[b * SDIM + tid + j * 256];
        m = fmaxf(m, vals[j]);
    }
#pragma unroll
    for (int off = 32; off; off >>= 1) m = fmaxf(m, __shfl_xor(m, off, 64));
    if (lane == 0) red[wave] = m;
    __syncthreads();
    float m4 = fmaxf(fmaxf(red[0], red[1]), fmaxf(red[2], red[3]));
    float sum = 0.f;
#pragma unroll
    for (int j = 0; j < 8; ++j) {
        vals[j] = __expf(vals[j] - m4);
        sum += vals[j];
    }
#pragma unroll
    for (int off = 32; off; off >>= 1) sum += __shfl_xor(sum, off, 64);
    if (lane == 0) red[4 + wave] = sum;
    __syncthreads();
    float inv = 1.f / (red[4] + red[5] + red[6] + red[7]);
#pragma unroll
    for (int j = 0; j < 8; ++j) out[b * SDIM + tid + j * 256] = vals[j] * inv;
}

extern "C" void kernel_launch(void* const* d_in, const int* in_sizes, int n_in,
                              void* d_out, int out_size, void* d_ws, size_t ws_size,
                              hipStream_t stream) {
    const float* hidden = (const float*)d_in[0];   // [1,B,H]
    const float* enc    = (const float*)d_in[1];   // [S,B,H]
    const float* W      = (const float*)d_in[2];   // [H,H]
    // d_in[3] = b_attn: constant per softmax row -> cancels, unused.
    float* out = (float*)d_out;                    // [B,1,S] fp32

    float* v = (float*)d_ws;                       // B*H floats   (128 KiB)
    float* e = v + BDIM * HDIM;                    // B*S floats   (256 KiB)

    k1_hidW  <<<BDIM * (HDIM / 256), 256, 0, stream>>>(hidden, W, v);
    k2_energy<<<(SDIM * BDIM) / 4,   256, 0, stream>>>(enc, v, e);
    k3_softmax<<<BDIM,               256, 0, stream>>>(e, out);
}

// Round 7
// 385.054 us; speedup vs baseline: 1.1022x; 1.1022x over previous
//
#include <hip/hip_runtime.h>
#include <math.h>

#define HDIM 1024
#define SDIM 2048
#define BDIM 32

// K1: v[b][h] = sum_k hidden[b][k] * W[k][h]
// grid = 32 b x 8 htiles = 256 blocks (all CUs), 128 threads (h-coalesced).
// 4 independent accumulators + unroll 8 -> 32 loads in flight, no dep chain.
__global__ void k1_hidW(const float* __restrict__ hidden,
                        const float* __restrict__ W,
                        float* __restrict__ v) {
    int tile = blockIdx.x & 7;
    int b    = blockIdx.x >> 3;
    int h    = tile * 128 + threadIdx.x;
    const float* hb = hidden + b * HDIM;
    float a0 = 0.f, a1 = 0.f, a2 = 0.f, a3 = 0.f;
#pragma unroll 8
    for (int k = 0; k < HDIM; k += 4) {
        a0 = fmaf(hb[k + 0], W[(size_t)(k + 0) * HDIM + h], a0);
        a1 = fmaf(hb[k + 1], W[(size_t)(k + 1) * HDIM + h], a1);
        a2 = fmaf(hb[k + 2], W[(size_t)(k + 2) * HDIM + h], a2);
        a3 = fmaf(hb[k + 3], W[(size_t)(k + 3) * HDIM + h], a3);
    }
    v[b * HDIM + h] = (a0 + a1) + (a2 + a3);
}

// K2: e[b][s] = dot(enc[s,b,:], v[b,:])
// One wave per (s,b) row. 4 waves/block -> 16384 blocks.
// Each lane: 4x float4 of enc (coalesced 1KiB/wave/instr) dotted with v (L2/L3-hot).
__global__ void k2_energy(const float* __restrict__ enc,
                          const float* __restrict__ v,
                          float* __restrict__ e) {
    int wave = threadIdx.x >> 6;
    int lane = threadIdx.x & 63;
    int p = blockIdx.x * 4 + wave;           // 0 .. S*B-1
    int b = p & (BDIM - 1);
    int s = p >> 5;                          // p / BDIM
    const float4* encp = (const float4*)(enc + (size_t)(s * BDIM + b) * HDIM);
    const float4* vp   = (const float4*)(v + b * HDIM);
    float acc = 0.f;
#pragma unroll
    for (int j = 0; j < 4; ++j) {
        float4 a = encp[lane + j * 64];
        float4 w = vp[lane + j * 64];
        acc += a.x * w.x + a.y * w.y + a.z * w.z + a.w * w.w;
    }
#pragma unroll
    for (int off = 32; off; off >>= 1) acc += __shfl_xor(acc, off, 64);
    if (lane == 0) e[b * SDIM + s] = acc;
}

// K3: softmax over s per b. One block per b, 256 threads x 8 vals.
__global__ void k3_softmax(const float* __restrict__ e,
                           float* __restrict__ out) {
    __shared__ float red[8];
    int b = blockIdx.x;
    int tid = threadIdx.x;
    int wave = tid >> 6, lane = tid & 63;
    float vals[8];
    float m = -INFINITY;
#pragma unroll
    for (int j = 0; j < 8; ++j) {
        vals[j] = e[b * SDIM + tid + j * 256];
        m = fmaxf(m, vals[j]);
    }
#pragma unroll
    for (int off = 32; off; off >>= 1) m = fmaxf(m, __shfl_xor(m, off, 64));
    if (lane == 0) red[wave] = m;
    __syncthreads();
    float m4 = fmaxf(fmaxf(red[0], red[1]), fmaxf(red[2], red[3]));
    float sum = 0.f;
#pragma unroll
    for (int j = 0; j < 8; ++j) {
        vals[j] = __expf(vals[j] - m4);
        sum += vals[j];
    }
#pragma unroll
    for (int off = 32; off; off >>= 1) sum += __shfl_xor(sum, off, 64);
    if (lane == 0) red[4 + wave] = sum;
    __syncthreads();
    float inv = 1.f / (red[4] + red[5] + red[6] + red[7]);
#pragma unroll
    for (int j = 0; j < 8; ++j) out[b * SDIM + tid + j * 256] = vals[j] * inv;
}

extern "C" void kernel_launch(void* const* d_in, const int* in_sizes, int n_in,
                              void* d_out, int out_size, void* d_ws, size_t ws_size,
                              hipStream_t stream) {
    const float* hidden = (const float*)d_in[0];   // [1,B,H]
    const float* enc    = (const float*)d_in[1];   // [S,B,H]
    const float* W      = (const float*)d_in[2];   // [H,H]
    // d_in[3] = b_attn: per-b constant -> cancels in softmax, unused.
    float* out = (float*)d_out;                    // [B,1,S] fp32

    float* v = (float*)d_ws;                       // B*H floats (128 KiB)
    float* e = v + BDIM * HDIM;                    // B*S floats (256 KiB)

    k1_hidW  <<<BDIM * 8,          128, 0, stream>>>(hidden, W, v);
    k2_energy<<<(SDIM * BDIM) / 4, 256, 0, stream>>>(enc, v, e);
    k3_softmax<<<BDIM,             256, 0, stream>>>(e, out);
}